// Round 7
// baseline (341.635 us; speedup 1.0000x reference)
//
#include <hip/hip_runtime.h>
#include <hip/hip_bf16.h>

#define NN 50000
#define NE 800000
#define DF 128
#define NSLICE 8
#define SLICEN 6250  // NN / NSLICE

typedef __bf16 bf16x8 __attribute__((ext_vector_type(8)));
typedef float f32x4 __attribute__((ext_vector_type(4)));

__device__ __forceinline__ unsigned short f32_to_bf16_rne(float f) {
    unsigned int u = __float_as_uint(f);
    u += 0x7fffu + ((u >> 16) & 1u);
    return (unsigned short)(u >> 16);
}

__device__ __forceinline__ unsigned int pack_bf16x2(float lo, float hi) {
    return (unsigned int)f32_to_bf16_rne(lo) | ((unsigned int)f32_to_bf16_rne(hi) << 16);
}

// ---------------- graph build (XCD-sliced: blockIdx&7 ~ XCD, each slice owns
// a contiguous 6250-node dst range so its col/deg region stays in one L2) ----
__global__ __launch_bounds__(256) void k_degree(const int* __restrict__ dst, int* __restrict__ deg, int e) {
    int slice = blockIdx.x & (NSLICE - 1);
    int blk = blockIdx.x >> 3;
    int stride = (gridDim.x >> 3) * 256;
    for (int i = blk * 256 + threadIdx.x; i < e; i += stride) {
        int d = dst[i];
        if (d / SLICEN == slice) atomicAdd(&deg[d], 1);
    }
}

__global__ __launch_bounds__(256) void k_scatter(const int* __restrict__ src, const int* __restrict__ dst,
                                                 int* __restrict__ cursor, int* __restrict__ col, int e) {
    int slice = blockIdx.x & (NSLICE - 1);
    int blk = blockIdx.x >> 3;
    int stride = (gridDim.x >> 3) * 256;
    for (int i = blk * 256 + threadIdx.x; i < e; i += stride) {
        int d = dst[i];
        if (d / SLICEN == slice) {
            int p = atomicAdd(&cursor[d], 1);
            col[p] = src[i];
        }
    }
}

__global__ __launch_bounds__(256) void k_scan1(const int* __restrict__ deg, int* __restrict__ part, int n) {
    __shared__ int sm[256];
    int i = blockIdx.x * 256 + threadIdx.x;
    int v = (i < n) ? deg[i] : 0;
    sm[threadIdx.x] = v;
    __syncthreads();
    for (int s = 128; s > 0; s >>= 1) {
        if (threadIdx.x < s) sm[threadIdx.x] += sm[threadIdx.x + s];
        __syncthreads();
    }
    if (threadIdx.x == 0) part[blockIdx.x] = sm[0];
}

__global__ __launch_bounds__(256) void k_scan2(int* __restrict__ part, int nblk, int* __restrict__ row_ptr,
                                               int n, int etot) {
    __shared__ int sm[256];
    int t = threadIdx.x;
    int v = (t < nblk) ? part[t] : 0;
    sm[t] = v;
    __syncthreads();
    for (int off = 1; off < 256; off <<= 1) {
        int x = (t >= off) ? sm[t - off] : 0;
        __syncthreads();
        sm[t] += x;
        __syncthreads();
    }
    if (t < nblk) part[t] = sm[t] - v;  // exclusive block offsets
    if (t == 0) row_ptr[n] = etot;
}

__global__ __launch_bounds__(256) void k_scan3(const int* __restrict__ deg, const int* __restrict__ part,
                                               int* __restrict__ row_ptr, int* __restrict__ cursor,
                                               float* __restrict__ inv_deg, int n) {
    __shared__ int sm[256];
    int i = blockIdx.x * 256 + threadIdx.x;
    int t = threadIdx.x;
    int v = (i < n) ? deg[i] : 0;
    sm[t] = v;
    __syncthreads();
    for (int off = 1; off < 256; off <<= 1) {
        int x = (t >= off) ? sm[t - off] : 0;
        __syncthreads();
        sm[t] += x;
        __syncthreads();
    }
    if (i < n) {
        int excl = sm[t] - v + part[blockIdx.x];
        row_ptr[i] = excl;
        cursor[i] = excl;
        inv_deg[i] = 1.0f / (float)((v > 1) ? v : 1);
    }
}

// ---------------- fused dtype convert: feats + 6 weight matrices ------------
__global__ __launch_bounds__(256) void k_f2b_all(const float* __restrict__ feats,
                                                 const float* __restrict__ w0, const float* __restrict__ w1,
                                                 const float* __restrict__ w2, const float* __restrict__ w3,
                                                 const float* __restrict__ w4, const float* __restrict__ w5,
                                                 unsigned short* __restrict__ h_bf,
                                                 unsigned short* __restrict__ Wb) {
    int i = (blockIdx.x * 256 + threadIdx.x) * 4;
    const float* fsrc;
    unsigned short* dstp;
    if (i < NN * DF) {
        fsrc = feats + i;
        dstp = h_bf + i;
    } else {
        int j = i - NN * DF;
        if (j >= 6 * DF * DF) return;
        int w = j >> 14;       // which weight matrix (16384 elems each)
        int o = j & 16383;
        const float* ws[6] = {w0, w1, w2, w3, w4, w5};
        fsrc = ws[w] + o;
        dstp = Wb + w * DF * DF + o;
    }
    float4 v = *reinterpret_cast<const float4*>(fsrc);
    ushort4 r;
    r.x = f32_to_bf16_rne(v.x);
    r.y = f32_to_bf16_rne(v.y);
    r.z = f32_to_bf16_rne(v.z);
    r.w = f32_to_bf16_rne(v.w);
    *reinterpret_cast<ushort4*>(dstp) = r;
}

// ---------------- fused layer: agg(64 rows)->LDS, then MFMA GEMM ------------
// out = relu(Hin@Ws^T + mean_neigh(Hin)@Wn^T + bias), written to Hout (bf16)
// or Fout (f32). Hout must NOT alias Hin (ping-pong).
__global__ __launch_bounds__(256) void k_layer(const unsigned short* __restrict__ Hin,
                                               const int* __restrict__ row_ptr, const int* __restrict__ col,
                                               const float* __restrict__ inv_deg,
                                               const unsigned short* __restrict__ Wb,  // Ws | Wn
                                               const float* __restrict__ bias,
                                               unsigned short* __restrict__ Hout,
                                               float* __restrict__ Fout,
                                               int n) {
    __shared__ unsigned short aggs[64][136];  // +8 pad: row stride 272B, 2-way banks max
    int brow = blockIdx.x * 64;
    int lane = threadIdx.x & 63;
    int wid = threadIdx.x >> 6;
    int g = lane >> 4;
    int l = lane & 15;
    int off = l * 8;

    // ---- Phase A: each wave aggregates 16 nodes (4 neighbors x 16 lanes) ----
    for (int t = 0; t < 16; ++t) {
        int node = brow + wid * 16 + t;
        float a[8];
#pragma unroll
        for (int k = 0; k < 8; ++k) a[k] = 0.f;
        float iv = 0.f;
        if (node < n) {
            int s = row_ptr[node], e = row_ptr[node + 1];
            iv = inv_deg[node];
            for (int j = s; j < e; j += 8) {
                int j0 = j + g;
                int j1 = j + 4 + g;
                if (j0 < e) {
                    int c = col[j0];
                    uint4 u = *reinterpret_cast<const uint4*>(Hin + (size_t)c * DF + off);
                    a[0] += __uint_as_float(u.x << 16);
                    a[1] += __uint_as_float(u.x & 0xffff0000u);
                    a[2] += __uint_as_float(u.y << 16);
                    a[3] += __uint_as_float(u.y & 0xffff0000u);
                    a[4] += __uint_as_float(u.z << 16);
                    a[5] += __uint_as_float(u.z & 0xffff0000u);
                    a[6] += __uint_as_float(u.w << 16);
                    a[7] += __uint_as_float(u.w & 0xffff0000u);
                }
                if (j1 < e) {
                    int c = col[j1];
                    uint4 u = *reinterpret_cast<const uint4*>(Hin + (size_t)c * DF + off);
                    a[0] += __uint_as_float(u.x << 16);
                    a[1] += __uint_as_float(u.x & 0xffff0000u);
                    a[2] += __uint_as_float(u.y << 16);
                    a[3] += __uint_as_float(u.y & 0xffff0000u);
                    a[4] += __uint_as_float(u.z << 16);
                    a[5] += __uint_as_float(u.z & 0xffff0000u);
                    a[6] += __uint_as_float(u.w << 16);
                    a[7] += __uint_as_float(u.w & 0xffff0000u);
                }
            }
        }
#pragma unroll
        for (int k = 0; k < 8; ++k) {
            a[k] += __shfl_xor(a[k], 16, 64);
            a[k] += __shfl_xor(a[k], 32, 64);
        }
        if (g == 0) {
            uint4 r;
            r.x = pack_bf16x2(a[0] * iv, a[1] * iv);
            r.y = pack_bf16x2(a[2] * iv, a[3] * iv);
            r.z = pack_bf16x2(a[4] * iv, a[5] * iv);
            r.w = pack_bf16x2(a[6] * iv, a[7] * iv);
            *reinterpret_cast<uint4*>(&aggs[wid * 16 + t][off]) = r;
        }
    }
    __syncthreads();

    // ---- Phase B: GEMM. wave w owns output cols [32w, 32w+32). ----
    int l15 = l;
    int lk = g * 8;
    int colb = wid * 32;

    f32x4 zero = {0.f, 0.f, 0.f, 0.f};
    f32x4 acc[4][2];
#pragma unroll
    for (int m = 0; m < 4; ++m) {
        acc[m][0] = zero;
        acc[m][1] = zero;
    }

    // self term: A from global Hin
#pragma unroll
    for (int ks = 0; ks < 4; ++ks) {
        int kb = ks * 32 + lk;
        bf16x8 bfr0 = *reinterpret_cast<const bf16x8*>(Wb + (colb + l15) * DF + kb);
        bf16x8 bfr1 = *reinterpret_cast<const bf16x8*>(Wb + (colb + 16 + l15) * DF + kb);
#pragma unroll
        for (int m = 0; m < 4; ++m) {
            int r = brow + m * 16 + l15;
            if (r >= n) r = n - 1;
            bf16x8 afr = *reinterpret_cast<const bf16x8*>(Hin + (size_t)r * DF + kb);
            acc[m][0] = __builtin_amdgcn_mfma_f32_16x16x32_bf16(afr, bfr0, acc[m][0], 0, 0, 0);
            acc[m][1] = __builtin_amdgcn_mfma_f32_16x16x32_bf16(afr, bfr1, acc[m][1], 0, 0, 0);
        }
    }
    // neigh term: A from LDS aggs
    const unsigned short* Wn = Wb + DF * DF;
#pragma unroll
    for (int ks = 0; ks < 4; ++ks) {
        int kb = ks * 32 + lk;
        bf16x8 bfr0 = *reinterpret_cast<const bf16x8*>(Wn + (colb + l15) * DF + kb);
        bf16x8 bfr1 = *reinterpret_cast<const bf16x8*>(Wn + (colb + 16 + l15) * DF + kb);
#pragma unroll
        for (int m = 0; m < 4; ++m) {
            bf16x8 afr = *reinterpret_cast<const bf16x8*>(&aggs[m * 16 + l15][kb]);
            acc[m][0] = __builtin_amdgcn_mfma_f32_16x16x32_bf16(afr, bfr0, acc[m][0], 0, 0, 0);
            acc[m][1] = __builtin_amdgcn_mfma_f32_16x16x32_bf16(afr, bfr1, acc[m][1], 0, 0, 0);
        }
    }

    int rb = g * 4;
#pragma unroll
    for (int q = 0; q < 2; ++q) {
        int o = colb + q * 16 + l15;
        float bv = bias[o];
#pragma unroll
        for (int m = 0; m < 4; ++m) {
#pragma unroll
            for (int j = 0; j < 4; ++j) {
                int r = brow + m * 16 + rb + j;
                if (r < n) {
                    float v = fmaxf(acc[m][q][j] + bv, 0.f);
                    if (Fout) Fout[(size_t)r * DF + o] = v;
                    else Hout[(size_t)r * DF + o] = f32_to_bf16_rne(v);
                }
            }
        }
    }
}

extern "C" void kernel_launch(void* const* d_in, const int* in_sizes, int n_in,
                              void* d_out, int out_size, void* d_ws, size_t ws_size,
                              hipStream_t stream) {
    const float* feats = (const float*)d_in[0];
    const int* src = (const int*)d_in[1];
    const int* dst = (const int*)d_in[2];
    const float* bias[3] = {(const float*)d_in[5], (const float*)d_in[8], (const float*)d_in[11]};

    char* ws = (char*)d_ws;
    unsigned short* h_bf = (unsigned short*)(ws);                 // 12,800,000 B
    unsigned short* h1 = (unsigned short*)(ws + 12800000);        // 12,800,000 B (ping-pong)
    unsigned short* Wb = (unsigned short*)(ws + 25600000);        // 196,608 B
    int* deg = (int*)(ws + 25796608);                             // 200,000 B
    int* row_ptr = (int*)(ws + 25996608);                         // 200,004 B
    int* cursor = (int*)(ws + 26196624);                          // 200,000 B
    float* inv_deg = (float*)(ws + 26396624);                     // 200,000 B
    int* col = (int*)(ws + 26596624);                             // 3,200,000 B
    int* part = (int*)(ws + 29796624);                            // 1,024 B

    hipMemsetAsync(deg, 0, NN * sizeof(int), stream);
    k_degree<<<512, 256, 0, stream>>>(dst, deg, NE);
    int nblk = (NN + 255) / 256;  // 196
    k_scan1<<<nblk, 256, 0, stream>>>(deg, part, NN);
    k_scan2<<<1, 256, 0, stream>>>(part, nblk, row_ptr, NN, NE);
    k_scan3<<<nblk, 256, 0, stream>>>(deg, part, row_ptr, cursor, inv_deg, NN);
    k_scatter<<<512, 256, 0, stream>>>(src, dst, cursor, col, NE);

    int qtot = (NN * DF + 6 * DF * DF) / 4;
    k_f2b_all<<<(qtot + 255) / 256, 256, 0, stream>>>(
        feats, (const float*)d_in[3], (const float*)d_in[4], (const float*)d_in[6],
        (const float*)d_in[7], (const float*)d_in[9], (const float*)d_in[10], h_bf, Wb);

    int gblk = (NN + 63) / 64;  // 782
    k_layer<<<gblk, 256, 0, stream>>>(h_bf, row_ptr, col, inv_deg, Wb, bias[0], h1, nullptr, NN);
    k_layer<<<gblk, 256, 0, stream>>>(h1, row_ptr, col, inv_deg, Wb + 2 * DF * DF, bias[1], h_bf, nullptr, NN);
    k_layer<<<gblk, 256, 0, stream>>>(h_bf, row_ptr, col, inv_deg, Wb + 4 * DF * DF, bias[2], nullptr,
                                      (float*)d_out, NN);
}

// Round 8
// 301.975 us; speedup vs baseline: 1.1313x; 1.1313x over previous
//
#include <hip/hip_runtime.h>
#include <hip/hip_bf16.h>

#define NN 50000
#define NE 800000
#define DF 128
#define NSLICE 8
#define SLICEN 6250  // NN / NSLICE

typedef __bf16 bf16x8 __attribute__((ext_vector_type(8)));
typedef float f32x4 __attribute__((ext_vector_type(4)));

__device__ __forceinline__ unsigned short f32_to_bf16_rne(float f) {
    unsigned int u = __float_as_uint(f);
    u += 0x7fffu + ((u >> 16) & 1u);
    return (unsigned short)(u >> 16);
}

__device__ __forceinline__ unsigned int pack_bf16x2(float lo, float hi) {
    return (unsigned int)f32_to_bf16_rne(lo) | ((unsigned int)f32_to_bf16_rne(hi) << 16);
}

// ---------------- graph build (XCD-sliced: blockIdx&7 ~ XCD, each slice owns
// a contiguous 6250-node dst range so its col/deg region stays in one L2) ----
__global__ __launch_bounds__(256) void k_degree(const int* __restrict__ dst, int* __restrict__ deg, int e) {
    int slice = blockIdx.x & (NSLICE - 1);
    int blk = blockIdx.x >> 3;
    int stride = (gridDim.x >> 3) * 256;
    for (int i = blk * 256 + threadIdx.x; i < e; i += stride) {
        int d = dst[i];
        if (d / SLICEN == slice) atomicAdd(&deg[d], 1);
    }
}

__global__ __launch_bounds__(256) void k_scatter(const int* __restrict__ src, const int* __restrict__ dst,
                                                 int* __restrict__ cursor, int* __restrict__ col, int e) {
    int slice = blockIdx.x & (NSLICE - 1);
    int blk = blockIdx.x >> 3;
    int stride = (gridDim.x >> 3) * 256;
    for (int i = blk * 256 + threadIdx.x; i < e; i += stride) {
        int d = dst[i];
        if (d / SLICEN == slice) {
            int p = atomicAdd(&cursor[d], 1);
            col[p] = src[i];
        }
    }
}

__global__ __launch_bounds__(256) void k_scan1(const int* __restrict__ deg, int* __restrict__ part, int n) {
    __shared__ int sm[256];
    int i = blockIdx.x * 256 + threadIdx.x;
    int v = (i < n) ? deg[i] : 0;
    sm[threadIdx.x] = v;
    __syncthreads();
    for (int s = 128; s > 0; s >>= 1) {
        if (threadIdx.x < s) sm[threadIdx.x] += sm[threadIdx.x + s];
        __syncthreads();
    }
    if (threadIdx.x == 0) part[blockIdx.x] = sm[0];
}

__global__ __launch_bounds__(256) void k_scan2(int* __restrict__ part, int nblk, int* __restrict__ row_ptr,
                                               int n, int etot) {
    __shared__ int sm[256];
    int t = threadIdx.x;
    int v = (t < nblk) ? part[t] : 0;
    sm[t] = v;
    __syncthreads();
    for (int off = 1; off < 256; off <<= 1) {
        int x = (t >= off) ? sm[t - off] : 0;
        __syncthreads();
        sm[t] += x;
        __syncthreads();
    }
    if (t < nblk) part[t] = sm[t] - v;  // exclusive block offsets
    if (t == 0) row_ptr[n] = etot;
}

__global__ __launch_bounds__(256) void k_scan3(const int* __restrict__ deg, const int* __restrict__ part,
                                               int* __restrict__ row_ptr, int* __restrict__ cursor,
                                               float* __restrict__ inv_deg, int n) {
    __shared__ int sm[256];
    int i = blockIdx.x * 256 + threadIdx.x;
    int t = threadIdx.x;
    int v = (i < n) ? deg[i] : 0;
    sm[t] = v;
    __syncthreads();
    for (int off = 1; off < 256; off <<= 1) {
        int x = (t >= off) ? sm[t - off] : 0;
        __syncthreads();
        sm[t] += x;
        __syncthreads();
    }
    if (i < n) {
        int excl = sm[t] - v + part[blockIdx.x];
        row_ptr[i] = excl;
        cursor[i] = excl;
        inv_deg[i] = 1.0f / (float)((v > 1) ? v : 1);
    }
}

// ---------------- fused dtype convert: feats + 6 weight matrices ------------
__global__ __launch_bounds__(256) void k_f2b_all(const float* __restrict__ feats,
                                                 const float* __restrict__ w0, const float* __restrict__ w1,
                                                 const float* __restrict__ w2, const float* __restrict__ w3,
                                                 const float* __restrict__ w4, const float* __restrict__ w5,
                                                 unsigned short* __restrict__ h_bf,
                                                 unsigned short* __restrict__ Wb) {
    int i = (blockIdx.x * 256 + threadIdx.x) * 4;
    const float* fsrc;
    unsigned short* dstp;
    if (i < NN * DF) {
        fsrc = feats + i;
        dstp = h_bf + i;
    } else {
        int j = i - NN * DF;
        if (j >= 6 * DF * DF) return;
        int w = j >> 14;       // which weight matrix (16384 elems each)
        int o = j & 16383;
        const float* ws[6] = {w0, w1, w2, w3, w4, w5};
        fsrc = ws[w] + o;
        dstp = Wb + w * DF * DF + o;
    }
    float4 v = *reinterpret_cast<const float4*>(fsrc);
    ushort4 r;
    r.x = f32_to_bf16_rne(v.x);
    r.y = f32_to_bf16_rne(v.y);
    r.z = f32_to_bf16_rne(v.z);
    r.w = f32_to_bf16_rne(v.w);
    *reinterpret_cast<ushort4*>(dstp) = r;
}

// ---------------- aggregation v2: one wave per node, 12500 blocks ----------
// 4 groups of 16 lanes; group g handles neighbor j+g, lane owns 8 feats
// (16B dwordx4). Unroll x2 -> 8 independent row-gathers in flight per wave.
__global__ __launch_bounds__(256) void k_agg(const unsigned short* __restrict__ H,
                                             const int* __restrict__ row_ptr, const int* __restrict__ col,
                                             const float* __restrict__ inv_deg,
                                             unsigned short* __restrict__ Agg, int n) {
    int wid = threadIdx.x >> 6;
    int lane = threadIdx.x & 63;
    int node = blockIdx.x * 4 + wid;
    if (node >= n) return;
    int s = row_ptr[node], e = row_ptr[node + 1];
    int g = lane >> 4;
    int l = lane & 15;
    int off = l * 8;  // 8 bf16 per lane

    float a[8];
#pragma unroll
    for (int k = 0; k < 8; ++k) a[k] = 0.f;

    for (int j = s; j < e; j += 8) {
        int j0 = j + g;
        int j1 = j + 4 + g;
        if (j0 < e) {
            int c = col[j0];
            uint4 u = *reinterpret_cast<const uint4*>(H + (size_t)c * DF + off);
            a[0] += __uint_as_float(u.x << 16);
            a[1] += __uint_as_float(u.x & 0xffff0000u);
            a[2] += __uint_as_float(u.y << 16);
            a[3] += __uint_as_float(u.y & 0xffff0000u);
            a[4] += __uint_as_float(u.z << 16);
            a[5] += __uint_as_float(u.z & 0xffff0000u);
            a[6] += __uint_as_float(u.w << 16);
            a[7] += __uint_as_float(u.w & 0xffff0000u);
        }
        if (j1 < e) {
            int c = col[j1];
            uint4 u = *reinterpret_cast<const uint4*>(H + (size_t)c * DF + off);
            a[0] += __uint_as_float(u.x << 16);
            a[1] += __uint_as_float(u.x & 0xffff0000u);
            a[2] += __uint_as_float(u.y << 16);
            a[3] += __uint_as_float(u.y & 0xffff0000u);
            a[4] += __uint_as_float(u.z << 16);
            a[5] += __uint_as_float(u.z & 0xffff0000u);
            a[6] += __uint_as_float(u.w << 16);
            a[7] += __uint_as_float(u.w & 0xffff0000u);
        }
    }

#pragma unroll
    for (int k = 0; k < 8; ++k) {
        a[k] += __shfl_xor(a[k], 16, 64);
        a[k] += __shfl_xor(a[k], 32, 64);
    }

    if (g == 0) {
        float iv = inv_deg[node];
        uint4 r;
        r.x = pack_bf16x2(a[0] * iv, a[1] * iv);
        r.y = pack_bf16x2(a[2] * iv, a[3] * iv);
        r.z = pack_bf16x2(a[4] * iv, a[5] * iv);
        r.w = pack_bf16x2(a[6] * iv, a[7] * iv);
        *reinterpret_cast<uint4*>(Agg + (size_t)node * DF + off) = r;
    }
}

// ---------------- fused GEMM: out = relu(Hb@Ws^T + Ab@Wn^T + bias) ----------
// BM=64 rows/block, 4 waves, wave w owns output cols [32w,32w+32). K=256.
// In-place safe: block writes only its own 64 rows, after __syncthreads.
__global__ __launch_bounds__(256) void k_gemm(const unsigned short* __restrict__ Hb,
                                              const unsigned short* __restrict__ Ab,
                                              const unsigned short* __restrict__ Wb,  // Ws | Wn (bf16)
                                              const float* __restrict__ bias,
                                              unsigned short* __restrict__ Hout,  // may alias Hb (or null)
                                              float* __restrict__ Fout,           // f32 out (or null)
                                              int n) {
    int brow = blockIdx.x * 64;
    int lane = threadIdx.x & 63;
    int wid = threadIdx.x >> 6;
    int l15 = lane & 15;
    int lk = (lane >> 4) * 8;
    int colb = wid * 32;

    f32x4 zero = {0.f, 0.f, 0.f, 0.f};
    f32x4 acc[4][2];
#pragma unroll
    for (int m = 0; m < 4; ++m) {
        acc[m][0] = zero;
        acc[m][1] = zero;
    }

#pragma unroll
    for (int ph = 0; ph < 2; ++ph) {
        const unsigned short* Ap = ph ? Ab : Hb;
        const unsigned short* Wp = Wb + ph * (DF * DF);
#pragma unroll
        for (int ks = 0; ks < 4; ++ks) {
            int kb = ks * 32 + lk;
            bf16x8 bfr0 = *reinterpret_cast<const bf16x8*>(Wp + (colb + l15) * DF + kb);
            bf16x8 bfr1 = *reinterpret_cast<const bf16x8*>(Wp + (colb + 16 + l15) * DF + kb);
#pragma unroll
            for (int m = 0; m < 4; ++m) {
                int r = brow + m * 16 + l15;
                if (r >= n) r = n - 1;
                bf16x8 afr = *reinterpret_cast<const bf16x8*>(Ap + (size_t)r * DF + kb);
                acc[m][0] = __builtin_amdgcn_mfma_f32_16x16x32_bf16(afr, bfr0, acc[m][0], 0, 0, 0);
                acc[m][1] = __builtin_amdgcn_mfma_f32_16x16x32_bf16(afr, bfr1, acc[m][1], 0, 0, 0);
            }
        }
    }

    __syncthreads();  // in-place safety: all waves' A reads complete before any store

    int rb = (lane >> 4) * 4;
#pragma unroll
    for (int q = 0; q < 2; ++q) {
        int o = colb + q * 16 + l15;
        float bv = bias[o];
#pragma unroll
        for (int m = 0; m < 4; ++m) {
#pragma unroll
            for (int j = 0; j < 4; ++j) {
                int r = brow + m * 16 + rb + j;
                if (r < n) {
                    float v = fmaxf(acc[m][q][j] + bv, 0.f);
                    if (Fout) Fout[(size_t)r * DF + o] = v;
                    else Hout[(size_t)r * DF + o] = f32_to_bf16_rne(v);
                }
            }
        }
    }
}

extern "C" void kernel_launch(void* const* d_in, const int* in_sizes, int n_in,
                              void* d_out, int out_size, void* d_ws, size_t ws_size,
                              hipStream_t stream) {
    const float* feats = (const float*)d_in[0];
    const int* src = (const int*)d_in[1];
    const int* dst = (const int*)d_in[2];
    const float* bias[3] = {(const float*)d_in[5], (const float*)d_in[8], (const float*)d_in[11]};

    char* ws = (char*)d_ws;
    unsigned short* h_bf = (unsigned short*)(ws);                 // 12,800,000 B
    unsigned short* agg_bf = (unsigned short*)(ws + 12800000);    // 12,800,000 B
    unsigned short* Wb = (unsigned short*)(ws + 25600000);        // 196,608 B
    int* deg = (int*)(ws + 25796608);                             // 200,000 B
    int* row_ptr = (int*)(ws + 25996608);                         // 200,004 B
    int* cursor = (int*)(ws + 26196624);                          // 200,000 B
    float* inv_deg = (float*)(ws + 26396624);                     // 200,000 B
    int* col = (int*)(ws + 26596624);                             // 3,200,000 B
    int* part = (int*)(ws + 29796624);                            // 1,024 B

    hipMemsetAsync(deg, 0, NN * sizeof(int), stream);
    k_degree<<<512, 256, 0, stream>>>(dst, deg, NE);
    int nblk = (NN + 255) / 256;  // 196
    k_scan1<<<nblk, 256, 0, stream>>>(deg, part, NN);
    k_scan2<<<1, 256, 0, stream>>>(part, nblk, row_ptr, NN, NE);
    k_scan3<<<nblk, 256, 0, stream>>>(deg, part, row_ptr, cursor, inv_deg, NN);
    k_scatter<<<512, 256, 0, stream>>>(src, dst, cursor, col, NE);

    int qtot = (NN * DF + 6 * DF * DF) / 4;
    k_f2b_all<<<(qtot + 255) / 256, 256, 0, stream>>>(
        feats, (const float*)d_in[3], (const float*)d_in[4], (const float*)d_in[6],
        (const float*)d_in[7], (const float*)d_in[9], (const float*)d_in[10], h_bf, Wb);

    int gblk = (NN + 63) / 64;  // 782
    for (int l = 0; l < 3; ++l) {
        k_agg<<<(NN + 3) / 4, 256, 0, stream>>>(h_bf, row_ptr, col, inv_deg, agg_bf, NN);
        const unsigned short* Wl = Wb + l * 2 * DF * DF;
        if (l < 2)
            k_gemm<<<gblk, 256, 0, stream>>>(h_bf, agg_bf, Wl, bias[l], h_bf, nullptr, NN);
        else
            k_gemm<<<gblk, 256, 0, stream>>>(h_bf, agg_bf, Wl, bias[l], nullptr, (float*)d_out, NN);
    }
}

// Round 10
// 260.548 us; speedup vs baseline: 1.3112x; 1.1590x over previous
//
#include <hip/hip_runtime.h>
#include <hip/hip_bf16.h>

#define NN 50000
#define NE 800000
#define DF 128
#define NSL 128      // dst slices for bucket sort
#define SLN 391      // nodes per slice (128*391 = 50048 >= NN)
#define CAP 8192     // bucket capacity per slice (avg 6250, Poisson sigma~79)
#define ECHUNK 1563  // edges per k_bucket block (512*1563 >= NE)

typedef __bf16 bf16x8 __attribute__((ext_vector_type(8)));
typedef float f32x4 __attribute__((ext_vector_type(4)));

__device__ __forceinline__ unsigned short f32_to_bf16_rne(float f) {
    unsigned int u = __float_as_uint(f);
    u += 0x7fffu + ((u >> 16) & 1u);
    return (unsigned short)(u >> 16);
}

__device__ __forceinline__ unsigned int pack_bf16x2(float lo, float hi) {
    return (unsigned int)f32_to_bf16_rne(lo) | ((unsigned int)f32_to_bf16_rne(hi) << 16);
}

// ---------------- graph build v3: two-level bucket sort -------------------
// Phase 1: bucket edges by dst-slice. Per-block LDS counts, one reservation
// atomic per (block,slice), then append (src,dst) pairs into slice regions.
__global__ __launch_bounds__(256) void k_bucket(const int* __restrict__ src, const int* __restrict__ dst,
                                                int* __restrict__ gcur, uint2* __restrict__ bucket) {
    __shared__ int cnt[NSL];
    __shared__ int rb[NSL];
    int t = threadIdx.x;
    for (int j = t; j < NSL; j += 256) cnt[j] = 0;
    __syncthreads();
    int base = blockIdx.x * ECHUNK;
    int end = base + ECHUNK;
    if (end > NE) end = NE;
    for (int i = base + t; i < end; i += 256) atomicAdd(&cnt[dst[i] / SLN], 1);
    __syncthreads();
    for (int j = t; j < NSL; j += 256) rb[j] = atomicAdd(&gcur[j], cnt[j]);
    __syncthreads();
    for (int j = t; j < NSL; j += 256) cnt[j] = rb[j];  // reuse as write cursor
    __syncthreads();
    for (int i = base + t; i < end; i += 256) {
        int d = dst[i];
        int s = d / SLN;
        int pos = atomicAdd(&cnt[s], 1);
        bucket[s * CAP + pos] = make_uint2((unsigned)src[i], (unsigned)d);
    }
}

// Phase 1b: tiny scan of 128 slice counts -> per-slice CSR base offsets.
__global__ void k_sbase(const int* __restrict__ gcur, int* __restrict__ sbase, int* __restrict__ row_ptr) {
    if (threadIdx.x == 0) {
        int acc = 0;
        for (int s = 0; s < NSL; ++s) {
            sbase[s] = acc;
            acc += gcur[s];
        }
        row_ptr[NN] = acc;  // == NE
    }
}

// Phase 2: one block per slice. Count degrees in LDS, scan, write row_ptr /
// inv_deg, then place edges via LDS cursors. col writes stay in a ~50KB
// L1/L2-resident window -> lines fill completely before writeback.
__global__ __launch_bounds__(256) void k_cslice(const uint2* __restrict__ bucket, const int* __restrict__ gcur,
                                                const int* __restrict__ sbase, int* __restrict__ col,
                                                int* __restrict__ row_ptr, float* __restrict__ inv_deg) {
    __shared__ int sdeg[512];
    __shared__ int scur[512];
    int s = blockIdx.x;
    int t = threadIdx.x;
    int nbase = s * SLN;
    int ncnt = NN - nbase;
    if (ncnt > SLN) ncnt = SLN;
    int ecnt = gcur[s];
    int eb = s * CAP;
    int cb = sbase[s];
    sdeg[t] = 0;
    sdeg[t + 256] = 0;
    __syncthreads();
    for (int e = t; e < ecnt; e += 256) atomicAdd(&sdeg[bucket[eb + e].y - nbase], 1);
    __syncthreads();
    int d0 = sdeg[t], d1 = sdeg[t + 256];
    for (int off = 1; off < 512; off <<= 1) {
        int v0 = (t >= off) ? sdeg[t - off] : 0;
        int v1 = (t + 256 >= off) ? sdeg[t + 256 - off] : 0;
        __syncthreads();
        sdeg[t] += v0;
        sdeg[t + 256] += v1;
        __syncthreads();
    }
    int e0 = sdeg[t] - d0, e1 = sdeg[t + 256] - d1;  // exclusive scan
    scur[t] = e0;
    scur[t + 256] = e1;
    if (t < ncnt) {
        row_ptr[nbase + t] = cb + e0;
        inv_deg[nbase + t] = 1.0f / (float)(d0 > 1 ? d0 : 1);
    }
    if (t + 256 < ncnt) {
        row_ptr[nbase + t + 256] = cb + e1;
        inv_deg[nbase + t + 256] = 1.0f / (float)(d1 > 1 ? d1 : 1);
    }
    __syncthreads();
    for (int e = t; e < ecnt; e += 256) {
        uint2 pr = bucket[eb + e];
        int p = atomicAdd(&scur[pr.y - nbase], 1);
        col[cb + p] = (int)pr.x;
    }
}

// ---------------- fused dtype convert: feats + 6 weight matrices ------------
__global__ __launch_bounds__(256) void k_f2b_all(const float* __restrict__ feats,
                                                 const float* __restrict__ w0, const float* __restrict__ w1,
                                                 const float* __restrict__ w2, const float* __restrict__ w3,
                                                 const float* __restrict__ w4, const float* __restrict__ w5,
                                                 unsigned short* __restrict__ h_bf,
                                                 unsigned short* __restrict__ Wb) {
    int i = (blockIdx.x * 256 + threadIdx.x) * 4;
    const float* fsrc;
    unsigned short* dstp;
    if (i < NN * DF) {
        fsrc = feats + i;
        dstp = h_bf + i;
    } else {
        int j = i - NN * DF;
        if (j >= 6 * DF * DF) return;
        int w = j >> 14;  // which weight matrix (16384 elems each)
        int o = j & 16383;
        const float* ws[6] = {w0, w1, w2, w3, w4, w5};
        fsrc = ws[w] + o;
        dstp = Wb + w * DF * DF + o;
    }
    float4 v = *reinterpret_cast<const float4*>(fsrc);
    ushort4 r;
    r.x = f32_to_bf16_rne(v.x);
    r.y = f32_to_bf16_rne(v.y);
    r.z = f32_to_bf16_rne(v.z);
    r.w = f32_to_bf16_rne(v.w);
    *reinterpret_cast<ushort4*>(dstp) = r;
}

// ---------------- aggregation v2: one wave per node, 12500 blocks ----------
__global__ __launch_bounds__(256) void k_agg(const unsigned short* __restrict__ H,
                                             const int* __restrict__ row_ptr, const int* __restrict__ col,
                                             const float* __restrict__ inv_deg,
                                             unsigned short* __restrict__ Agg, int n) {
    int wid = threadIdx.x >> 6;
    int lane = threadIdx.x & 63;
    int node = blockIdx.x * 4 + wid;
    if (node >= n) return;
    int s = row_ptr[node], e = row_ptr[node + 1];
    int g = lane >> 4;
    int l = lane & 15;
    int off = l * 8;  // 8 bf16 per lane

    float a[8];
#pragma unroll
    for (int k = 0; k < 8; ++k) a[k] = 0.f;

    for (int j = s; j < e; j += 8) {
        int j0 = j + g;
        int j1 = j + 4 + g;
        if (j0 < e) {
            int c = col[j0];
            uint4 u = *reinterpret_cast<const uint4*>(H + (size_t)c * DF + off);
            a[0] += __uint_as_float(u.x << 16);
            a[1] += __uint_as_float(u.x & 0xffff0000u);
            a[2] += __uint_as_float(u.y << 16);
            a[3] += __uint_as_float(u.y & 0xffff0000u);
            a[4] += __uint_as_float(u.z << 16);
            a[5] += __uint_as_float(u.z & 0xffff0000u);
            a[6] += __uint_as_float(u.w << 16);
            a[7] += __uint_as_float(u.w & 0xffff0000u);
        }
        if (j1 < e) {
            int c = col[j1];
            uint4 u = *reinterpret_cast<const uint4*>(H + (size_t)c * DF + off);
            a[0] += __uint_as_float(u.x << 16);
            a[1] += __uint_as_float(u.x & 0xffff0000u);
            a[2] += __uint_as_float(u.y << 16);
            a[3] += __uint_as_float(u.y & 0xffff0000u);
            a[4] += __uint_as_float(u.z << 16);
            a[5] += __uint_as_float(u.z & 0xffff0000u);
            a[6] += __uint_as_float(u.w << 16);
            a[7] += __uint_as_float(u.w & 0xffff0000u);
        }
    }

#pragma unroll
    for (int k = 0; k < 8; ++k) {
        a[k] += __shfl_xor(a[k], 16, 64);
        a[k] += __shfl_xor(a[k], 32, 64);
    }

    if (g == 0) {
        float iv = inv_deg[node];
        uint4 r;
        r.x = pack_bf16x2(a[0] * iv, a[1] * iv);
        r.y = pack_bf16x2(a[2] * iv, a[3] * iv);
        r.z = pack_bf16x2(a[4] * iv, a[5] * iv);
        r.w = pack_bf16x2(a[6] * iv, a[7] * iv);
        *reinterpret_cast<uint4*>(Agg + (size_t)node * DF + off) = r;
    }
}

// ---------------- fused GEMM: out = relu(Hb@Ws^T + Ab@Wn^T + bias) ----------
// BM=64 rows/block, 4 waves, wave w owns output cols [32w,32w+32). K=256.
// In-place safe: block writes only its own 64 rows, after __syncthreads.
__global__ __launch_bounds__(256) void k_gemm(const unsigned short* __restrict__ Hb,
                                              const unsigned short* __restrict__ Ab,
                                              const unsigned short* __restrict__ Wb,  // Ws | Wn (bf16)
                                              const float* __restrict__ bias,
                                              unsigned short* __restrict__ Hout,  // may alias Hb (or null)
                                              float* __restrict__ Fout,           // f32 out (or null)
                                              int n) {
    int brow = blockIdx.x * 64;
    int lane = threadIdx.x & 63;
    int wid = threadIdx.x >> 6;
    int l15 = lane & 15;
    int lk = (lane >> 4) * 8;
    int colb = wid * 32;

    f32x4 zero = {0.f, 0.f, 0.f, 0.f};
    f32x4 acc[4][2];
#pragma unroll
    for (int m = 0; m < 4; ++m) {
        acc[m][0] = zero;
        acc[m][1] = zero;
    }

#pragma unroll
    for (int ph = 0; ph < 2; ++ph) {
        const unsigned short* Ap = ph ? Ab : Hb;
        const unsigned short* Wp = Wb + ph * (DF * DF);
#pragma unroll
        for (int ks = 0; ks < 4; ++ks) {
            int kb = ks * 32 + lk;
            bf16x8 bfr0 = *reinterpret_cast<const bf16x8*>(Wp + (colb + l15) * DF + kb);
            bf16x8 bfr1 = *reinterpret_cast<const bf16x8*>(Wp + (colb + 16 + l15) * DF + kb);
#pragma unroll
            for (int m = 0; m < 4; ++m) {
                int r = brow + m * 16 + l15;
                if (r >= n) r = n - 1;
                bf16x8 afr = *reinterpret_cast<const bf16x8*>(Ap + (size_t)r * DF + kb);
                acc[m][0] = __builtin_amdgcn_mfma_f32_16x16x32_bf16(afr, bfr0, acc[m][0], 0, 0, 0);
                acc[m][1] = __builtin_amdgcn_mfma_f32_16x16x32_bf16(afr, bfr1, acc[m][1], 0, 0, 0);
            }
        }
    }

    __syncthreads();  // in-place safety: all waves' A reads complete before any store

    int rb = (lane >> 4) * 4;
#pragma unroll
    for (int q = 0; q < 2; ++q) {
        int o = colb + q * 16 + l15;
        float bv = bias[o];
#pragma unroll
        for (int m = 0; m < 4; ++m) {
#pragma unroll
            for (int j = 0; j < 4; ++j) {
                int r = brow + m * 16 + rb + j;
                if (r < n) {
                    float v = fmaxf(acc[m][q][j] + bv, 0.f);
                    if (Fout) Fout[(size_t)r * DF + o] = v;
                    else Hout[(size_t)r * DF + o] = f32_to_bf16_rne(v);
                }
            }
        }
    }
}

extern "C" void kernel_launch(void* const* d_in, const int* in_sizes, int n_in,
                              void* d_out, int out_size, void* d_ws, size_t ws_size,
                              hipStream_t stream) {
    const float* feats = (const float*)d_in[0];
    const int* src = (const int*)d_in[1];
    const int* dst = (const int*)d_in[2];
    const float* bias[3] = {(const float*)d_in[5], (const float*)d_in[8], (const float*)d_in[11]};

    char* ws = (char*)d_ws;
    unsigned short* h_bf = (unsigned short*)(ws);                 // 12,800,000 B
    unsigned short* agg_bf = (unsigned short*)(ws + 12800000);    // 12,800,000 B
    uint2* bucket = (uint2*)(ws + 12800000);                      // 8,388,608 B (overlaid: build-phase only)
    unsigned short* Wb = (unsigned short*)(ws + 25600000);        // 196,608 B
    int* row_ptr = (int*)(ws + 25796608);                         // 200,008 B
    float* inv_deg = (float*)(ws + 25996616);                     // 200,000 B
    int* col = (int*)(ws + 26196616);                             // 3,200,000 B
    int* gcur = (int*)(ws + 29396616);                            // 512 B
    int* sbase = (int*)(ws + 29397128);                           // 512 B

    hipMemsetAsync(gcur, 0, NSL * sizeof(int), stream);
    k_bucket<<<512, 256, 0, stream>>>(src, dst, gcur, bucket);
    k_sbase<<<1, 64, 0, stream>>>(gcur, sbase, row_ptr);
    k_cslice<<<NSL, 256, 0, stream>>>(bucket, gcur, sbase, col, row_ptr, inv_deg);

    int qtot = (NN * DF + 6 * DF * DF) / 4;
    k_f2b_all<<<(qtot + 255) / 256, 256, 0, stream>>>(
        feats, (const float*)d_in[3], (const float*)d_in[4], (const float*)d_in[6],
        (const float*)d_in[7], (const float*)d_in[9], (const float*)d_in[10], h_bf, Wb);

    int gblk = (NN + 63) / 64;  // 782
    for (int l = 0; l < 3; ++l) {
        k_agg<<<(NN + 3) / 4, 256, 0, stream>>>(h_bf, row_ptr, col, inv_deg, agg_bf, NN);
        const unsigned short* Wl = Wb + l * 2 * DF * DF;
        if (l < 2)
            k_gemm<<<gblk, 256, 0, stream>>>(h_bf, agg_bf, Wl, bias[l], h_bf, nullptr, NN);
        else
            k_gemm<<<gblk, 256, 0, stream>>>(h_bf, agg_bf, Wl, bias[l], nullptr, (float*)d_out, NN);
    }
}